// Round 4
// baseline (1091.183 us; speedup 1.0000x reference)
//
#include <hip/hip_runtime.h>
#include <hip/hip_bf16.h>

#define BB 64
#define NN 6272      // H*W*C = 196*32
#define OO 10
#define CGRP 6       // c's (slots) per wave
#define NCG 6        // c-groups: 6*6=36 slots cover 32 c (4 dead)
#define HSTEP 7      // hw positions per wave
#define NHC 28       // 196/7 hw-chunks
#define WPB 4        // waves per block
#define BPB 42       // blocks per batch: 168 waves / 4
#define TPB 256
#define EPSF 1e-9f

// workspace offsets (floats)
#define ACC_PER_IT 21120            // B*O*33
#define OFF_ACC 0                   // 3 * 21120
#define OFF_MU  63360               // 2 * B*O*16
#define OFF_IV  83840               // 2 * B*O*16
#define OFF_BI  104320              // 2 * B*O

// Barrier-free layout: lane = slot*10 + o (6 slots x 10 o, lanes 60..63 idle).
// Each wave owns c = cg*6+slot (fixed -> w in regs) and walks 7 hw positions.
// The 10 logits of one n live in one wave -> softmax via 10 ds_bpermute
// shuffles; NO __syncthreads, NO __shared__ anywhere. (R3 post-mortem:
// iter0 == iter1 duration proved the per-step block barrier was the wall,
// not VALU.)
__global__ __launch_bounds__(TPB, 3) void fc_pass(
    const float* __restrict__ pose, const float* __restrict__ actv,
    const float* __restrict__ wgt,
    const float* __restrict__ muIn, const float* __restrict__ ivIn,
    const float* __restrict__ biIn,
    float* __restrict__ acc, int iter)
{
    const int t    = threadIdx.x;
    const int lane = t & 63;
    const int wv   = t >> 6;                  // 0..3
    const int b    = blockIdx.y;
    const int gw   = blockIdx.x * WPB + wv;   // 0..167
    const int cg   = gw % NCG;                // c-group
    const int hc   = gw / NCG;                // hw-chunk 0..27

    const int slot = lane / 10;               // 0..6 (6 only for idle lanes)
    const int o    = lane - slot * 10;        // 0..9
    const int craw = cg * CGRP + slot;
    const bool alive = (lane < 60) && (craw < 32);
    const int c    = min(craw, 31);

    // W[c][o] 4x4 in registers, wr[j*4+k]
    float wr[16];
    {
        const float4* wp = (const float4*)(wgt + ((c * OO + o) << 4));
        float4 a0 = wp[0], a1 = wp[1], a2 = wp[2], a3 = wp[3];
        wr[0]=a0.x; wr[1]=a0.y; wr[2]=a0.z; wr[3]=a0.w;
        wr[4]=a1.x; wr[5]=a1.y; wr[6]=a1.z; wr[7]=a1.w;
        wr[8]=a2.x; wr[9]=a2.y; wr[10]=a2.z; wr[11]=a2.w;
        wr[12]=a3.x; wr[13]=a3.y; wr[14]=a3.z; wr[15]=a3.w;
    }

    float mu[16], iv[16], bias = 0.f;
    if (iter > 0) {
        const float4* mp = (const float4*)(muIn + (((size_t)b * OO + o) << 4));
        const float4* vp = (const float4*)(ivIn + (((size_t)b * OO + o) << 4));
        float4 m0=mp[0], m1=mp[1], m2=mp[2], m3=mp[3];
        mu[0]=m0.x; mu[1]=m0.y; mu[2]=m0.z; mu[3]=m0.w;
        mu[4]=m1.x; mu[5]=m1.y; mu[6]=m1.z; mu[7]=m1.w;
        mu[8]=m2.x; mu[9]=m2.y; mu[10]=m2.z; mu[11]=m2.w;
        mu[12]=m3.x; mu[13]=m3.y; mu[14]=m3.z; mu[15]=m3.w;
        float4 v0=vp[0], v1=vp[1], v2=vp[2], v3=vp[3];
        iv[0]=v0.x; iv[1]=v0.y; iv[2]=v0.z; iv[3]=v0.w;
        iv[4]=v1.x; iv[5]=v1.y; iv[6]=v1.z; iv[7]=v1.w;
        iv[8]=v2.x; iv[9]=v2.y; iv[10]=v2.z; iv[11]=v2.w;
        iv[12]=v3.x; iv[13]=v3.y; iv[14]=v3.z; iv[15]=v3.w;
        bias = biIn[b * OO + o];
    }

    float S[33];
    #pragma unroll
    for (int k = 0; k < 33; k++) S[k] = 0.f;

    const int gb = slot * 10;                  // softmax gather base lane

    for (int s = 0; s < HSTEP; s++) {
        const int hw = hc * HSTEP + s;         // wave-uniform -> SGPR math
        const int hi = hw / 14;
        const int wi = hw - hi * 14;
        const float offw = (wi + 0.5f) * (1.0f / 14.0f);
        const float offh = (hi + 0.5f) * (1.0f / 14.0f);
        const int n = (hw << 5) + c;           // c<=31 -> always in-bounds
        const size_t row = (size_t)b * NN + n;

        const float4* pp = (const float4*)(pose + row * 16);
        float4 q0 = pp[0], q1 = pp[1], q2 = pp[2], q3 = pp[3];
        float a = actv[row];
        if (!alive) a = 0.f;

        float p[16];
        p[0]=q0.x; p[1]=q0.y; p[2]=q0.z; p[3]=q0.w;
        p[4]=q1.x; p[5]=q1.y; p[6]=q1.z; p[7]=q1.w;
        p[8]=q2.x; p[9]=q2.y; p[10]=q2.z; p[11]=q2.w;
        p[12]=q3.x; p[13]=q3.y; p[14]=q3.z; p[15]=q3.w;

        // votes (coord-addition folded in)
        float v[16];
        #pragma unroll
        for (int ii = 0; ii < 4; ii++) {
            #pragma unroll
            for (int kk = 0; kk < 4; kk++) {
                float vv = fmaf(p[ii*4+0], wr[0*4+kk],
                           fmaf(p[ii*4+1], wr[1*4+kk],
                           fmaf(p[ii*4+2], wr[2*4+kk],
                                p[ii*4+3] * wr[3*4+kk])));
                if (ii == 0 && kk == 3) vv += offw;
                if (ii == 1 && kk == 3) vv += offh;
                v[ii*4+kk] = vv;
            }
        }

        float rr;
        if (iter > 0) {
            float sq = 0.f;
            #pragma unroll
            for (int d = 0; d < 16; d++) {
                const float dm = v[d] - mu[d];
                sq = fmaf(dm * dm, iv[d], sq);
            }
            const float lg = bias - 0.5f * sq;
            // gather the slot's 10 logits (intra-wave, no barrier)
            float lgs[OO];
            #pragma unroll
            for (int j = 0; j < OO; j++)
                lgs[j] = __shfl(lg, min(gb + j, 63), 64);
            float mx = lgs[0];
            #pragma unroll
            for (int j = 1; j < OO; j++) mx = fmaxf(mx, lgs[j]);
            float sum = 0.f;
            #pragma unroll
            for (int j = 0; j < OO; j++) sum += __expf(lgs[j] - mx);
            rr = __expf(lg - mx) * a / sum;
        } else {
            rr = 0.1f * a;    // uniform routing * activation
        }

        #pragma unroll
        for (int d = 0; d < 16; d++) {
            const float rv = rr * v[d];
            S[d] += rv;
            S[16 + d] = fmaf(rv, v[d], S[16 + d]);
        }
        S[32] += rr;
    }

    // reduce the 6 slots of each o down to lanes 0..9, then atomics.
    // round 1: lane l<30 gains slot(l/10)+3; round 2: lanes<10 add the
    // (1+4) and (2+5) pair-sums. Reads precede writes within each round.
    const int l30 = min(lane + 30, 63);
    const int l10 = min(lane + 10, 63);
    const int l20 = min(lane + 20, 63);
    #pragma unroll
    for (int k = 0; k < 33; k++) {
        float x = S[k];
        x += __shfl(x, l30, 64);
        const float x2 = __shfl(x, l10, 64);
        const float x3 = __shfl(x, l20, 64);
        S[k] = x + x2 + x3;
    }
    if (lane < 10) {
        float* ab = acc + ((size_t)b * OO + lane) * 33;
        #pragma unroll
        for (int k = 0; k < 33; k++) atomicAdd(&ab[k], S[k]);
    }
}

__global__ __launch_bounds__(256) void fc_stats(
    const float* __restrict__ acc, const float* __restrict__ beta_a,
    const float* __restrict__ beta_u,
    float* __restrict__ muOut, float* __restrict__ ivOut, float* __restrict__ biOut,
    float* __restrict__ out, float inv_temp, int final_it)
{
    const int t = threadIdx.x;
    const int b = blockIdx.x;
    if (t >= 160) return;
    const int o = t >> 4, d = t & 15;
    const float* ab = acc + ((size_t)b * OO + o) * 33;
    const float S1 = ab[d], S2 = ab[16 + d], S0 = ab[32];
    const float rs = S0 + EPSF;
    const float mu = S1 / rs;
    float vraw = fmaf(mu * mu, S0, fmaf(-2.f * mu, S1, S2));
    vraw = fmaxf(vraw, 0.f);
    const float var = vraw / rs + EPSF;
    const float lv = __logf(var);
    float sv = lv;
    #pragma unroll
    for (int off = 8; off >= 1; off >>= 1) sv += __shfl_xor(sv, off, 16);
    const float cost = rs * fmaf(0.5f, sv, 16.f * beta_u[o]);
    const float av = 1.f / (1.f + __expf(-inv_temp * (beta_a[o] - cost)));
    if (!final_it) {
        muOut[((size_t)b * OO + o) * 16 + d] = mu;
        ivOut[((size_t)b * OO + o) * 16 + d] = 1.f / var;
        if (d == 0) biOut[b * OO + o] = __logf(av + EPSF) - 0.5f * sv;
    } else {
        out[((size_t)b * OO + o) * 16 + d] = mu;               // pose_out (B,O,16)
        if (d == 0) out[BB * OO * 16 + b * OO + o] = av;       // act_out (B,O)
    }
}

extern "C" void kernel_launch(void* const* d_in, const int* in_sizes, int n_in,
                              void* d_out, int out_size, void* d_ws, size_t ws_size,
                              hipStream_t stream) {
    const float* pose   = (const float*)d_in[0];
    const float* actv   = (const float*)d_in[1];
    const float* wgt    = (const float*)d_in[2];
    const float* beta_a = (const float*)d_in[3];
    const float* beta_u = (const float*)d_in[4];
    float* out = (float*)d_out;
    float* ws  = (float*)d_ws;

    hipMemsetAsync(ws + OFF_ACC, 0, (size_t)3 * ACC_PER_IT * sizeof(float), stream);

    float* acc0 = ws + OFF_ACC;
    float* acc1 = ws + OFF_ACC + ACC_PER_IT;
    float* acc2 = ws + OFF_ACC + 2 * ACC_PER_IT;
    float* mu0 = ws + OFF_MU;            float* mu1 = ws + OFF_MU + 10240;
    float* iv0 = ws + OFF_IV;            float* iv1 = ws + OFF_IV + 10240;
    float* bi0 = ws + OFF_BI;            float* bi1 = ws + OFF_BI + 640;

    dim3 pgrid(BPB, BB), pblk(TPB);
    fc_pass<<<pgrid, pblk, 0, stream>>>(pose, actv, wgt, nullptr, nullptr, nullptr, acc0, 0);
    fc_stats<<<BB, 256, 0, stream>>>(acc0, beta_a, beta_u, mu0, iv0, bi0, out, 1.0f, 0);
    fc_pass<<<pgrid, pblk, 0, stream>>>(pose, actv, wgt, mu0, iv0, bi0, acc1, 1);
    fc_stats<<<BB, 256, 0, stream>>>(acc1, beta_a, beta_u, mu1, iv1, bi1, out, 2.0f, 0);
    fc_pass<<<pgrid, pblk, 0, stream>>>(pose, actv, wgt, mu1, iv1, bi1, acc2, 2);
    fc_stats<<<BB, 256, 0, stream>>>(acc2, beta_a, beta_u, nullptr, nullptr, nullptr, out, 3.0f, 1);
}

// Round 5
// 1066.440 us; speedup vs baseline: 1.0232x; 1.0232x over previous
//
#include <hip/hip_runtime.h>
#include <hip/hip_bf16.h>

#define BB 64
#define NN 6272      // H*W*C = 196*32
#define OO 10
#define CGRP 6       // c's (slots) per wave
#define NCG 6        // c-groups: 6*6=36 slots cover 32 c (4 dead)
#define HSTEP 7      // hw positions per wave
#define WPB 4        // waves per block
#define BPB 42       // blocks per batch: 168 waves / 4
#define TPB 256
#define EPSF 1e-9f

// workspace offsets (floats)
#define ACC_PER_IT 21120            // B*O*33
#define OFF_ACC 0                   // 3 * 21120
#define OFF_MU  63360               // 2 * B*O*16
#define OFF_IV  83840               // 2 * B*O*16
#define OFF_BI  104320              // 2 * B*O

// Barrier-free layout: lane = slot*10 + o (6 slots x 10 o, lanes 60..63 idle).
// Each wave owns c = cg*6+slot (fixed -> w in regs) and walks 7 hw positions.
// Softmax = 10 intra-wave shuffles; NO __syncthreads, NO __shared__.
// __launch_bounds__(256, 2): cap 256 arch VGPRs. R4 used (256,3)-equivalent
// pressure and the allocator SPILLED TO SCRATCH: WRITE_SIZE 1.5->142 MB,
// 375us/pass pure spill traffic. ~200 live floats need the 256 cap.
__global__ __launch_bounds__(TPB, 2) void fc_pass(
    const float* __restrict__ pose, const float* __restrict__ actv,
    const float* __restrict__ wgt,
    const float* __restrict__ muIn, const float* __restrict__ ivIn,
    const float* __restrict__ biIn,
    float* __restrict__ acc, int iter)
{
    const int t    = threadIdx.x;
    const int lane = t & 63;
    const int wv   = t >> 6;                  // 0..3
    const int b    = blockIdx.y;
    const int gw   = blockIdx.x * WPB + wv;   // 0..167
    const int cg   = gw % NCG;                // c-group
    const int hc   = gw / NCG;                // hw-chunk 0..27

    const int slot = lane / 10;               // 0..6 (6 only for idle lanes)
    const int o    = lane - slot * 10;        // 0..9
    const int craw = cg * CGRP + slot;
    const bool alive = (lane < 60) && (craw < 32);
    const int c    = min(craw, 31);

    // W[c][o] 4x4 in registers, wr[j*4+k]
    float wr[16];
    {
        const float4* wp = (const float4*)(wgt + ((c * OO + o) << 4));
        float4 a0 = wp[0], a1 = wp[1], a2 = wp[2], a3 = wp[3];
        wr[0]=a0.x; wr[1]=a0.y; wr[2]=a0.z; wr[3]=a0.w;
        wr[4]=a1.x; wr[5]=a1.y; wr[6]=a1.z; wr[7]=a1.w;
        wr[8]=a2.x; wr[9]=a2.y; wr[10]=a2.z; wr[11]=a2.w;
        wr[12]=a3.x; wr[13]=a3.y; wr[14]=a3.z; wr[15]=a3.w;
    }

    float mu[16], iv[16], bias = 0.f;
    if (iter > 0) {
        const float4* mp = (const float4*)(muIn + (((size_t)b * OO + o) << 4));
        const float4* vp = (const float4*)(ivIn + (((size_t)b * OO + o) << 4));
        float4 m0=mp[0], m1=mp[1], m2=mp[2], m3=mp[3];
        mu[0]=m0.x; mu[1]=m0.y; mu[2]=m0.z; mu[3]=m0.w;
        mu[4]=m1.x; mu[5]=m1.y; mu[6]=m1.z; mu[7]=m1.w;
        mu[8]=m2.x; mu[9]=m2.y; mu[10]=m2.z; mu[11]=m2.w;
        mu[12]=m3.x; mu[13]=m3.y; mu[14]=m3.z; mu[15]=m3.w;
        float4 v0=vp[0], v1=vp[1], v2=vp[2], v3=vp[3];
        iv[0]=v0.x; iv[1]=v0.y; iv[2]=v0.z; iv[3]=v0.w;
        iv[4]=v1.x; iv[5]=v1.y; iv[6]=v1.z; iv[7]=v1.w;
        iv[8]=v2.x; iv[9]=v2.y; iv[10]=v2.z; iv[11]=v2.w;
        iv[12]=v3.x; iv[13]=v3.y; iv[14]=v3.z; iv[15]=v3.w;
        bias = biIn[b * OO + o];
    }

    float S1[16], S2[16], S0 = 0.f;
    #pragma unroll
    for (int d = 0; d < 16; d++) { S1[d] = 0.f; S2[d] = 0.f; }

    const int gb = slot * 10;                  // softmax gather base lane
    const size_t rowB = (size_t)b * NN + c;    // + (hw<<5)

    // software prefetch: step s+1's loads issue before step s's compute
    int hw = hc * HSTEP;
    float4 q0, q1, q2, q3;  float a;
    {
        const float4* pp = (const float4*)(pose + (rowB + (hw << 5)) * 16);
        q0 = pp[0]; q1 = pp[1]; q2 = pp[2]; q3 = pp[3];
        a = actv[rowB + (hw << 5)];
    }

    for (int s = 0; s < HSTEP; s++) {
        float4 n0, n1, n2, n3;  float na = 0.f;
        if (s + 1 < HSTEP) {
            const float4* np = (const float4*)(pose + (rowB + ((hw + 1) << 5)) * 16);
            n0 = np[0]; n1 = np[1]; n2 = np[2]; n3 = np[3];
            na = actv[rowB + ((hw + 1) << 5)];
        }

        const int hi = hw / 14;
        const int wi = hw - hi * 14;
        const float offw = (wi + 0.5f) * (1.0f / 14.0f);
        const float offh = (hi + 0.5f) * (1.0f / 14.0f);

        float p[16];
        p[0]=q0.x; p[1]=q0.y; p[2]=q0.z; p[3]=q0.w;
        p[4]=q1.x; p[5]=q1.y; p[6]=q1.z; p[7]=q1.w;
        p[8]=q2.x; p[9]=q2.y; p[10]=q2.z; p[11]=q2.w;
        p[12]=q3.x; p[13]=q3.y; p[14]=q3.z; p[15]=q3.w;
        float av = alive ? a : 0.f;

        // votes (coord-addition folded in)
        float v[16];
        #pragma unroll
        for (int ii = 0; ii < 4; ii++) {
            #pragma unroll
            for (int kk = 0; kk < 4; kk++) {
                float vv = fmaf(p[ii*4+0], wr[0*4+kk],
                           fmaf(p[ii*4+1], wr[1*4+kk],
                           fmaf(p[ii*4+2], wr[2*4+kk],
                                p[ii*4+3] * wr[3*4+kk])));
                if (ii == 0 && kk == 3) vv += offw;
                if (ii == 1 && kk == 3) vv += offh;
                v[ii*4+kk] = vv;
            }
        }

        float rr;
        if (iter > 0) {
            float sq = 0.f;
            #pragma unroll
            for (int d = 0; d < 16; d++) {
                const float dm = v[d] - mu[d];
                sq = fmaf(dm * dm, iv[d], sq);
            }
            const float lg = bias - 0.5f * sq;
            // gather this slot's 10 logits (intra-wave, no barrier)
            float lgs[OO];
            #pragma unroll
            for (int j = 0; j < OO; j++)
                lgs[j] = __shfl(lg, min(gb + j, 63), 64);
            float mx = lgs[0];
            #pragma unroll
            for (int j = 1; j < OO; j++) mx = fmaxf(mx, lgs[j]);
            float sum = 0.f;
            #pragma unroll
            for (int j = 0; j < OO; j++) sum += __expf(lgs[j] - mx);
            rr = __expf(lg - mx) * av / sum;
        } else {
            rr = 0.1f * av;    // uniform routing * activation
        }

        #pragma unroll
        for (int d = 0; d < 16; d++) {
            const float rv = rr * v[d];
            S1[d] += rv;
            S2[d] = fmaf(rv, v[d], S2[d]);
        }
        S0 += rr;

        q0 = n0; q1 = n1; q2 = n2; q3 = n3; a = na;
        hw++;
    }

    // reduce the 6 slots of each o down to lanes 0..9, then atomics.
    const int l30 = min(lane + 30, 63);
    const int l10 = min(lane + 10, 63);
    const int l20 = min(lane + 20, 63);
    float red[33];
    #pragma unroll
    for (int k = 0; k < 33; k++) {
        float x = (k < 16) ? S1[k] : ((k < 32) ? S2[k - 16] : S0);
        x += __shfl(x, l30, 64);
        const float x2 = __shfl(x, l10, 64);
        const float x3 = __shfl(x, l20, 64);
        red[k] = x + x2 + x3;
    }
    if (lane < 10) {
        float* ab = acc + ((size_t)b * OO + lane) * 33;
        #pragma unroll
        for (int k = 0; k < 33; k++) atomicAdd(&ab[k], red[k]);
    }
}

__global__ __launch_bounds__(256) void fc_stats(
    const float* __restrict__ acc, const float* __restrict__ beta_a,
    const float* __restrict__ beta_u,
    float* __restrict__ muOut, float* __restrict__ ivOut, float* __restrict__ biOut,
    float* __restrict__ out, float inv_temp, int final_it)
{
    const int t = threadIdx.x;
    const int b = blockIdx.x;
    if (t >= 160) return;
    const int o = t >> 4, d = t & 15;
    const float* ab = acc + ((size_t)b * OO + o) * 33;
    const float S1 = ab[d], S2 = ab[16 + d], S0 = ab[32];
    const float rs = S0 + EPSF;
    const float mu = S1 / rs;
    float vraw = fmaf(mu * mu, S0, fmaf(-2.f * mu, S1, S2));
    vraw = fmaxf(vraw, 0.f);
    const float var = vraw / rs + EPSF;
    const float lv = __logf(var);
    float sv = lv;
    #pragma unroll
    for (int off = 8; off >= 1; off >>= 1) sv += __shfl_xor(sv, off, 16);
    const float cost = rs * fmaf(0.5f, sv, 16.f * beta_u[o]);
    const float av = 1.f / (1.f + __expf(-inv_temp * (beta_a[o] - cost)));
    if (!final_it) {
        muOut[((size_t)b * OO + o) * 16 + d] = mu;
        ivOut[((size_t)b * OO + o) * 16 + d] = 1.f / var;
        if (d == 0) biOut[b * OO + o] = __logf(av + EPSF) - 0.5f * sv;
    } else {
        out[((size_t)b * OO + o) * 16 + d] = mu;               // pose_out (B,O,16)
        if (d == 0) out[BB * OO * 16 + b * OO + o] = av;       // act_out (B,O)
    }
}

extern "C" void kernel_launch(void* const* d_in, const int* in_sizes, int n_in,
                              void* d_out, int out_size, void* d_ws, size_t ws_size,
                              hipStream_t stream) {
    const float* pose   = (const float*)d_in[0];
    const float* actv   = (const float*)d_in[1];
    const float* wgt    = (const float*)d_in[2];
    const float* beta_a = (const float*)d_in[3];
    const float* beta_u = (const float*)d_in[4];
    float* out = (float*)d_out;
    float* ws  = (float*)d_ws;

    hipMemsetAsync(ws + OFF_ACC, 0, (size_t)3 * ACC_PER_IT * sizeof(float), stream);

    float* acc0 = ws + OFF_ACC;
    float* acc1 = ws + OFF_ACC + ACC_PER_IT;
    float* acc2 = ws + OFF_ACC + 2 * ACC_PER_IT;
    float* mu0 = ws + OFF_MU;            float* mu1 = ws + OFF_MU + 10240;
    float* iv0 = ws + OFF_IV;            float* iv1 = ws + OFF_IV + 10240;
    float* bi0 = ws + OFF_BI;            float* bi1 = ws + OFF_BI + 640;

    dim3 pgrid(BPB, BB), pblk(TPB);
    fc_pass<<<pgrid, pblk, 0, stream>>>(pose, actv, wgt, nullptr, nullptr, nullptr, acc0, 0);
    fc_stats<<<BB, 256, 0, stream>>>(acc0, beta_a, beta_u, mu0, iv0, bi0, out, 1.0f, 0);
    fc_pass<<<pgrid, pblk, 0, stream>>>(pose, actv, wgt, mu0, iv0, bi0, acc1, 1);
    fc_stats<<<BB, 256, 0, stream>>>(acc1, beta_a, beta_u, mu1, iv1, bi1, out, 2.0f, 0);
    fc_pass<<<pgrid, pblk, 0, stream>>>(pose, actv, wgt, mu1, iv1, bi1, acc2, 2);
    fc_stats<<<BB, 256, 0, stream>>>(acc2, beta_a, beta_u, nullptr, nullptr, nullptr, out, 3.0f, 1);
}

// Round 6
// 238.083 us; speedup vs baseline: 4.5832x; 4.4793x over previous
//
#include <hip/hip_runtime.h>
#include <hip/hip_bf16.h>

#define BB 64
#define NN 6272      // H*W*C = 196*32
#define OO 10
#define SSL 14       // grid.x: hi == blockIdx.x; 448 n per block
#define NSTEP 14     // wi steps per block
#define TPB 320      // 32 c x 10 o
#define EPSF 1e-9f

#define PST 18       // poseL row stride (even -> b64 aligned, 2-way bank alias = free)
#define PSS (32*PST) // poseL step stride = 576
#define LST 11       // logitL row stride (conflict-free)
#define LSS (32*LST) // logitL step stride = 352

// workspace offsets (floats)
#define ACC_PER_IT 21120            // B*O*33
#define OFF_ACC 0                   // 3 * 21120
#define OFF_MU  63360               // 2 * B*O*16
#define OFF_IV  83840               // 2 * B*O*16
#define OFF_BI  104320              // 2 * B*O

// Two-barrier structure. R3 proved the per-step __syncthreads was the wall
// (iter0 == iter1 duration at 30% VALUBusy); R4/R5 proved the shuffle-heavy
// barrier-free variant spills to scratch (WRITE_SIZE 110-142 MB). This keeps
// R3's spill-free register structure (60 VGPR) and batches the logit
// exchange: stage pose slice -> barrier -> all 14 logits -> barrier ->
// softmax+accumulate from LDS. No per-step barriers, no dynamic indexing.
__global__ __launch_bounds__(TPB, 3) void fc_pass(
    const float* __restrict__ pose, const float* __restrict__ actv,
    const float* __restrict__ wgt,
    const float* __restrict__ muIn, const float* __restrict__ ivIn,
    const float* __restrict__ biIn,
    float* __restrict__ acc, int iter)
{
    __shared__ __align__(16) float poseL[NSTEP * PSS];   // 32256 B
    __shared__ float logitL[NSTEP * LSS];                // 19712 B

    const int t = threadIdx.x;
    const int c = t & 31;
    const int o = t >> 5;           // 0..9
    const int ss = blockIdx.x;      // == hi
    const int b  = blockIdx.y;

    // ---- stage the block's 448 pose rows into LDS (coalesced f4 reads) ----
    {
        const float4* src = (const float4*)(pose + ((size_t)b * NN + ss * 448) * 16);
        for (int i4 = t; i4 < 448 * 4; i4 += TPB) {
            float4 val = src[i4];
            const int rc = i4 >> 2, d4 = i4 & 3;
            float* dst = &poseL[(rc >> 5) * PSS + (rc & 31) * PST + d4 * 4];
            ((float2*)dst)[0] = make_float2(val.x, val.y);
            ((float2*)dst)[1] = make_float2(val.z, val.w);
        }
    }

    // W[c][o] 4x4 in registers, wr[j*4+k]
    float wr[16];
    {
        const float4* wp = (const float4*)(wgt + ((c * OO + o) << 4));
        float4 a0 = wp[0], a1 = wp[1], a2 = wp[2], a3 = wp[3];
        wr[0]=a0.x; wr[1]=a0.y; wr[2]=a0.z; wr[3]=a0.w;
        wr[4]=a1.x; wr[5]=a1.y; wr[6]=a1.z; wr[7]=a1.w;
        wr[8]=a2.x; wr[9]=a2.y; wr[10]=a2.z; wr[11]=a2.w;
        wr[12]=a3.x; wr[13]=a3.y; wr[14]=a3.z; wr[15]=a3.w;
    }

    float mu[16], iv[16], bias = 0.f;
    if (iter > 0) {
        const float4* mp = (const float4*)(muIn + (((size_t)b * OO + o) << 4));
        const float4* vp = (const float4*)(ivIn + (((size_t)b * OO + o) << 4));
        float4 m0=mp[0], m1=mp[1], m2=mp[2], m3=mp[3];
        mu[0]=m0.x; mu[1]=m0.y; mu[2]=m0.z; mu[3]=m0.w;
        mu[4]=m1.x; mu[5]=m1.y; mu[6]=m1.z; mu[7]=m1.w;
        mu[8]=m2.x; mu[9]=m2.y; mu[10]=m2.z; mu[11]=m2.w;
        mu[12]=m3.x; mu[13]=m3.y; mu[14]=m3.z; mu[15]=m3.w;
        float4 v0=vp[0], v1=vp[1], v2=vp[2], v3=vp[3];
        iv[0]=v0.x; iv[1]=v0.y; iv[2]=v0.z; iv[3]=v0.w;
        iv[4]=v1.x; iv[5]=v1.y; iv[6]=v1.z; iv[7]=v1.w;
        iv[8]=v2.x; iv[9]=v2.y; iv[10]=v2.z; iv[11]=v2.w;
        iv[12]=v3.x; iv[13]=v3.y; iv[14]=v3.z; iv[15]=v3.w;
        bias = biIn[b * OO + o];
    }
    __syncthreads();

    const float offh = (ss + 0.5f) * (1.0f / 14.0f);

    // ---- phase 1: all 14 logits from LDS-resident pose ----
    if (iter > 0) {
        for (int s = 0; s < NSTEP; s++) {
            const float offw = (s + 0.5f) * (1.0f / 14.0f);
            const float* pr = &poseL[s * PSS + c * PST];
            float p[16];
            #pragma unroll
            for (int h = 0; h < 8; h++) {
                float2 u = ((const float2*)pr)[h];
                p[2*h] = u.x; p[2*h+1] = u.y;
            }
            float sq = 0.f;
            #pragma unroll
            for (int ii = 0; ii < 4; ii++) {
                #pragma unroll
                for (int kk = 0; kk < 4; kk++) {
                    float vv = fmaf(p[ii*4+0], wr[0*4+kk],
                               fmaf(p[ii*4+1], wr[1*4+kk],
                               fmaf(p[ii*4+2], wr[2*4+kk],
                                    p[ii*4+3] * wr[3*4+kk])));
                    if (ii == 0 && kk == 3) vv += offw;
                    if (ii == 1 && kk == 3) vv += offh;
                    const float dm = vv - mu[ii*4+kk];
                    sq = fmaf(dm * dm, iv[ii*4+kk], sq);
                }
            }
            logitL[s * LSS + c * LST + o] = bias - 0.5f * sq;
        }
        __syncthreads();
    }

    // ---- phase 2: softmax + accumulate (no barriers) ----
    float S1[16], S2[16], S0 = 0.f;
    #pragma unroll
    for (int d = 0; d < 16; d++) { S1[d] = 0.f; S2[d] = 0.f; }

    const float* arow = actv + (size_t)b * NN + ss * 448;

    for (int s = 0; s < NSTEP; s++) {
        const float a = arow[s * 32 + c];
        float rr;
        if (iter > 0) {
            float lgs[OO];
            #pragma unroll
            for (int j = 0; j < OO; j++) lgs[j] = logitL[s * LSS + c * LST + j];
            float mx = lgs[0];
            #pragma unroll
            for (int j = 1; j < OO; j++) mx = fmaxf(mx, lgs[j]);
            float sum = 0.f, own = 0.f;
            #pragma unroll
            for (int j = 0; j < OO; j++) {
                const float ef = __expf(lgs[j] - mx);
                sum += ef;
                own = (j == o) ? ef : own;     // cndmask, no dynamic index
            }
            rr = own * a / sum;
        } else {
            rr = 0.1f * a;
        }

        const float offw = (s + 0.5f) * (1.0f / 14.0f);
        const float* pr = &poseL[s * PSS + c * PST];
        float p[16];
        #pragma unroll
        for (int h = 0; h < 8; h++) {
            float2 u = ((const float2*)pr)[h];
            p[2*h] = u.x; p[2*h+1] = u.y;
        }
        #pragma unroll
        for (int ii = 0; ii < 4; ii++) {
            #pragma unroll
            for (int kk = 0; kk < 4; kk++) {
                float vv = fmaf(p[ii*4+0], wr[0*4+kk],
                           fmaf(p[ii*4+1], wr[1*4+kk],
                           fmaf(p[ii*4+2], wr[2*4+kk],
                                p[ii*4+3] * wr[3*4+kk])));
                if (ii == 0 && kk == 3) vv += offw;
                if (ii == 1 && kk == 3) vv += offh;
                const int d = ii*4+kk;
                const float rv = rr * vv;
                S1[d] += rv;
                S2[d] = fmaf(rv, vv, S2[d]);
            }
        }
        S0 += rr;
    }

    // ---- epilogue: R3's proven width-32 butterfly + atomics ----
    float* ab = acc + ((size_t)b * OO + o) * 33;
    float myred = 0.f;
    #pragma unroll
    for (int k = 0; k < 32; k++) {
        float tot = (k < 16) ? S1[k] : S2[k - 16];
        #pragma unroll
        for (int msk = 16; msk >= 1; msk >>= 1)
            tot += __shfl_xor(tot, msk, 32);
        if (c == k) myred = tot;
    }
    {
        float tot = S0;
        #pragma unroll
        for (int msk = 16; msk >= 1; msk >>= 1)
            tot += __shfl_xor(tot, msk, 32);
        if (c == 0) atomicAdd(&ab[32], tot);
    }
    atomicAdd(&ab[c], myred);
}

__global__ __launch_bounds__(256) void fc_stats(
    const float* __restrict__ acc, const float* __restrict__ beta_a,
    const float* __restrict__ beta_u,
    float* __restrict__ muOut, float* __restrict__ ivOut, float* __restrict__ biOut,
    float* __restrict__ out, float inv_temp, int final_it)
{
    const int t = threadIdx.x;
    const int b = blockIdx.x;
    if (t >= 160) return;
    const int o = t >> 4, d = t & 15;
    const float* ab = acc + ((size_t)b * OO + o) * 33;
    const float S1 = ab[d], S2 = ab[16 + d], S0 = ab[32];
    const float rs = S0 + EPSF;
    const float mu = S1 / rs;
    float vraw = fmaf(mu * mu, S0, fmaf(-2.f * mu, S1, S2));
    vraw = fmaxf(vraw, 0.f);
    const float var = vraw / rs + EPSF;
    const float lv = __logf(var);
    float sv = lv;
    #pragma unroll
    for (int off = 8; off >= 1; off >>= 1) sv += __shfl_xor(sv, off, 16);
    const float cost = rs * fmaf(0.5f, sv, 16.f * beta_u[o]);
    const float av = 1.f / (1.f + __expf(-inv_temp * (beta_a[o] - cost)));
    if (!final_it) {
        muOut[((size_t)b * OO + o) * 16 + d] = mu;
        ivOut[((size_t)b * OO + o) * 16 + d] = 1.f / var;
        if (d == 0) biOut[b * OO + o] = __logf(av + EPSF) - 0.5f * sv;
    } else {
        out[((size_t)b * OO + o) * 16 + d] = mu;               // pose_out (B,O,16)
        if (d == 0) out[BB * OO * 16 + b * OO + o] = av;       // act_out (B,O)
    }
}

extern "C" void kernel_launch(void* const* d_in, const int* in_sizes, int n_in,
                              void* d_out, int out_size, void* d_ws, size_t ws_size,
                              hipStream_t stream) {
    const float* pose   = (const float*)d_in[0];
    const float* actv   = (const float*)d_in[1];
    const float* wgt    = (const float*)d_in[2];
    const float* beta_a = (const float*)d_in[3];
    const float* beta_u = (const float*)d_in[4];
    float* out = (float*)d_out;
    float* ws  = (float*)d_ws;

    hipMemsetAsync(ws + OFF_ACC, 0, (size_t)3 * ACC_PER_IT * sizeof(float), stream);

    float* acc0 = ws + OFF_ACC;
    float* acc1 = ws + OFF_ACC + ACC_PER_IT;
    float* acc2 = ws + OFF_ACC + 2 * ACC_PER_IT;
    float* mu0 = ws + OFF_MU;            float* mu1 = ws + OFF_MU + 10240;
    float* iv0 = ws + OFF_IV;            float* iv1 = ws + OFF_IV + 10240;
    float* bi0 = ws + OFF_BI;            float* bi1 = ws + OFF_BI + 640;

    dim3 pgrid(SSL, BB), pblk(TPB);
    fc_pass<<<pgrid, pblk, 0, stream>>>(pose, actv, wgt, nullptr, nullptr, nullptr, acc0, 0);
    fc_stats<<<BB, 256, 0, stream>>>(acc0, beta_a, beta_u, mu0, iv0, bi0, out, 1.0f, 0);
    fc_pass<<<pgrid, pblk, 0, stream>>>(pose, actv, wgt, mu0, iv0, bi0, acc1, 1);
    fc_stats<<<BB, 256, 0, stream>>>(acc1, beta_a, beta_u, mu1, iv1, bi1, out, 2.0f, 0);
    fc_pass<<<pgrid, pblk, 0, stream>>>(pose, actv, wgt, mu1, iv1, bi1, acc2, 2);
    fc_stats<<<BB, 256, 0, stream>>>(acc2, beta_a, beta_u, nullptr, nullptr, nullptr, out, 3.0f, 1);
}